// Round 9
// baseline (214.464 us; speedup 1.0000x reference)
//
#include <hip/hip_runtime.h>

#define NN 10000
#define NE 160000
#define NG 512
#define DIN 128
#define DH 512
#define DOUT 16
#define NPAD 10112   // 158*64 (GEMM M-tile padding)

typedef __bf16 bf16_t;
typedef __attribute__((ext_vector_type(8))) __bf16 bf16x8;
typedef __attribute__((ext_vector_type(2))) __bf16 bf16x2;
typedef __attribute__((ext_vector_type(4))) float f32x4;
typedef __attribute__((ext_vector_type(2))) float f32x2;

// k_prep block ranges
#define LNB 2500                        // ln0: 4 rows/block
#define DEGB ((NE + 255) / 256)         // 625
#define WTE (512 * DIN + 3 * DH * DH)   // 851968
#define WTB ((WTE + 255) / 256)         // 3328
#define CURB ((NN + 255) / 256)         // 40

// ---------------- fused prep: ln0 + degree count + weight convert + cursor zero ----------------

__global__ __launch_bounds__(256) void k_prep(const float* __restrict__ x,
                                              const float* __restrict__ g0,
                                              const float* __restrict__ be0,
                                              bf16_t* __restrict__ lnx,
                                              const int* __restrict__ dst,
                                              int* __restrict__ deg,
                                              const float* __restrict__ W0,
                                              const float* __restrict__ Wh,
                                              bf16_t* __restrict__ Wt0,
                                              bf16_t* __restrict__ Wth,
                                              int* __restrict__ cursor) {
    int b = blockIdx.x;
    int tid = threadIdx.x;
    if (b < LNB) {
        int row = b * 4 + (tid >> 6);
        int lane = tid & 63;
        const float* xr = x + (size_t)row * DIN;
        float v0 = xr[lane], v1 = xr[lane + 64];
        float s = v0 + v1, s2 = v0 * v0 + v1 * v1;
#pragma unroll
        for (int off = 32; off; off >>= 1) {
            s += __shfl_xor(s, off);
            s2 += __shfl_xor(s2, off);
        }
        float mu = s * (1.f / 128.f);
        float var = s2 * (1.f / 128.f) - mu * mu;
        float r = rsqrtf(var + 1e-5f);
        bf16_t* yr = lnx + (size_t)row * DIN;
        yr[lane] = (bf16_t)((v0 - mu) * r * g0[lane] + be0[lane]);
        yr[lane + 64] = (bf16_t)((v1 - mu) * r * g0[lane + 64] + be0[lane + 64]);
    } else if (b < LNB + DEGB) {
        int e = (b - LNB) * 256 + tid;
        if (e < NE) atomicAdd(&deg[dst[e]], 1);
    } else if (b < LNB + DEGB + WTB) {
        int idx = (b - LNB - DEGB) * 256 + tid;
        if (idx < 512 * DIN) {
            int k = idx >> 9, n = idx & 511;   // W0 is [128][512]
            Wt0[n * DIN + k] = (bf16_t)W0[idx];
        } else if (idx < WTE) {
            int j = idx - 512 * DIN;
            int l = j >> 18;                   // / (512*512)
            int r2 = j & 262143;
            int k = r2 >> 9, n = r2 & 511;     // Wh[l] is [512][512]
            Wth[((size_t)l << 18) + n * DH + k] = (bf16_t)Wh[j];
        }
    } else {
        int i = (b - LNB - DEGB - WTB) * 256 + tid;
        if (i < NN) cursor[i] = 0;
    }
}

// ---------------- scan (rowptr) + dinv, wave-scan ----------------

__global__ __launch_bounds__(1024) void k_scan(const int* __restrict__ cnt,
                                               int* __restrict__ rowptr,
                                               float* __restrict__ dinv) {
    __shared__ int wsum[16];
    int tid = threadIdx.x, lane = tid & 63, wid = tid >> 6;
    const int PER = 10;
    int base = tid * PER;
    int local[PER];
    int s = 0;
#pragma unroll
    for (int i = 0; i < PER; ++i) {
        int idx = base + i;
        int v = (idx < NN) ? cnt[idx] : 0;
        if (idx < NN) dinv[idx] = rsqrtf((float)v + 1.0f);
        local[i] = s;
        s += v;
    }
    int mysum = s;
#pragma unroll
    for (int off = 1; off < 64; off <<= 1) {
        int v = __shfl_up(s, off);
        if (lane >= off) s += v;
    }
    if (lane == 63) wsum[wid] = s;
    __syncthreads();
    if (tid < 16) {
        int v = wsum[tid];
#pragma unroll
        for (int off = 1; off < 16; off <<= 1) {
            int u = __shfl_up(v, off);
            if (lane >= off) v += u;
        }
        wsum[tid] = v;
    }
    __syncthreads();
    int woff = (wid > 0) ? wsum[wid - 1] : 0;
    int excl = s - mysum + woff;
#pragma unroll
    for (int i = 0; i < PER; ++i) {
        int idx = base + i;
        if (idx < NN) rowptr[idx] = excl + local[i];
    }
    if (tid == 1023) rowptr[NN] = excl + mysum;
}

__global__ void k_fill_csr(const int* __restrict__ src, const int* __restrict__ dst,
                           const float* __restrict__ dinv, const int* __restrict__ rowptr,
                           int* __restrict__ cursor, int2* __restrict__ csr) {
    int e = blockIdx.x * blockDim.x + threadIdx.x;
    if (e >= NE) return;
    int s = src[e], d = dst[e];
    int pos = atomicAdd(&cursor[d], 1);
    csr[rowptr[d] + pos] = make_int2(s, __float_as_int(dinv[s] * dinv[d]));
}

// ---------------- standalone layernorm 512-wide bf16 -> bf16 ----------------

__global__ __launch_bounds__(256) void k_ln512(const bf16_t* __restrict__ x,
                                               const float* __restrict__ g,
                                               const float* __restrict__ b,
                                               bf16_t* __restrict__ y) {
    int row = blockIdx.x * 4 + (threadIdx.x >> 6);
    int lane = threadIdx.x & 63;
    if (row >= NN) return;
    int c0 = lane * 8;
    bf16x8 v = *(const bf16x8*)&x[(size_t)row * DH + c0];
    float f[8];
    float s = 0.f, s2 = 0.f;
#pragma unroll
    for (int i = 0; i < 8; ++i) {
        f[i] = (float)v[i];
        s += f[i];
        s2 += f[i] * f[i];
    }
#pragma unroll
    for (int off = 32; off; off >>= 1) {
        s += __shfl_xor(s, off);
        s2 += __shfl_xor(s2, off);
    }
    float mu = s * (1.f / 512.f);
    float var = s2 * (1.f / 512.f) - mu * mu;
    float r = rsqrtf(var + 1e-5f);
    f32x4 g0 = *(const f32x4*)&g[c0], g1 = *(const f32x4*)&g[c0 + 4];
    f32x4 b0 = *(const f32x4*)&b[c0], b1 = *(const f32x4*)&b[c0 + 4];
    bf16x8 o;
#pragma unroll
    for (int i = 0; i < 4; ++i) {
        o[i] = (bf16_t)((f[i] - mu) * r * g0[i] + b0[i]);
        o[i + 4] = (bf16_t)((f[i + 4] - mu) * r * g1[i] + b1[i]);
    }
    *(bf16x8*)&y[(size_t)row * DH + c0] = o;
}

// ---------------- bf16 MFMA GEMM: BM=64 BN=64 BK=128, 4 waves each 32x32 ----------------
// Single-buffered, 32 KB LDS; BK=128 halves barrier count vs BK=64 (4 K-steps at K=512).
// LDS XOR chunk swizzle (chunk ^= row&7), pre-swizzled global source.
// Rows are 256 B (16 chunks of 16 B); one 1 KB wave-issue covers 4 rows.

template <bool EPI>
__global__ __launch_bounds__(256) void k_gemm64(const bf16_t* __restrict__ A,
                                                const bf16_t* __restrict__ Bt,
                                                const float* __restrict__ bias,
                                                bf16_t* __restrict__ C, int K) {
    __shared__ bf16_t As[64 * 128];
    __shared__ bf16_t Bs[64 * 128];
    int tid = threadIdx.x;
    int lane = tid & 63, w = tid >> 6;
    int row0 = blockIdx.x * 64, col0 = blockIdx.y * 64;
    int wm = w >> 1, wn = w & 1;

    f32x4 acc[2][2];
#pragma unroll
    for (int i = 0; i < 2; ++i)
#pragma unroll
        for (int j = 0; j < 2; ++j) acc[i][j] = (f32x4){0.f, 0.f, 0.f, 0.f};

    int lr = lane >> 4;    // 0..3: row within 4-row issue group
    int lc = lane & 15;    // chunk slot 0..15

    for (int kt = 0; kt < K; kt += 128) {
#pragma unroll
        for (int i = 0; i < 4; ++i) {
            int r = w * 16 + i * 4 + lr;
            int cg = lc ^ (r & 7);   // pre-swizzled global chunk (XOR on low 3 bits)
            const bf16_t* srca = A + (size_t)(row0 + r) * K + kt + cg * 8;
            __builtin_amdgcn_global_load_lds(
                (const __attribute__((address_space(1))) void*)srca,
                (__attribute__((address_space(3))) void*)(As + (w * 16 + i * 4) * 128),
                16, 0, 0);
            const bf16_t* srcb = Bt + (size_t)(col0 + r) * K + kt + cg * 8;
            __builtin_amdgcn_global_load_lds(
                (const __attribute__((address_space(1))) void*)srcb,
                (__attribute__((address_space(3))) void*)(Bs + (w * 16 + i * 4) * 128),
                16, 0, 0);
        }
        __syncthreads();
#pragma unroll
        for (int ks = 0; ks < 4; ++ks) {
            bf16x8 af[2], bfr[2];
#pragma unroll
            for (int mi = 0; mi < 2; ++mi) {
                int mr = wm * 32 + mi * 16 + (lane & 15);
                int c = (ks * 4 + (lane >> 4)) ^ (mr & 7);
                af[mi] = *(const bf16x8*)&As[mr * 128 + c * 8];
            }
#pragma unroll
            for (int ni = 0; ni < 2; ++ni) {
                int nr = wn * 32 + ni * 16 + (lane & 15);
                int c = (ks * 4 + (lane >> 4)) ^ (nr & 7);
                bfr[ni] = *(const bf16x8*)&Bs[nr * 128 + c * 8];
            }
#pragma unroll
            for (int mi = 0; mi < 2; ++mi)
#pragma unroll
                for (int ni = 0; ni < 2; ++ni)
                    acc[mi][ni] = __builtin_amdgcn_mfma_f32_16x16x32_bf16(
                        af[mi], bfr[ni], acc[mi][ni], 0, 0, 0);
        }
        __syncthreads();
    }
#pragma unroll
    for (int mi = 0; mi < 2; ++mi)
#pragma unroll
        for (int ni = 0; ni < 2; ++ni) {
            int col = col0 + wn * 32 + ni * 16 + (lane & 15);
            float bv = EPI ? bias[col] : 0.f;
#pragma unroll
            for (int q = 0; q < 4; ++q) {
                int row = row0 + wm * 32 + mi * 16 + (lane >> 4) * 4 + q;
                float v = acc[mi][ni][q];
                if (EPI) v = fmaxf(v + bv, 0.f);
                C[(size_t)row * DH + col] = (bf16_t)v;
            }
        }
}

// ---------------- layer-0 aggregate, 128-wide, block per node, unroll-4 ----------------

__global__ __launch_bounds__(256) void k_agg128(const bf16_t* __restrict__ H,
                                                const int* __restrict__ rowptr,
                                                const int2* __restrict__ csr,
                                                const float* __restrict__ dinv,
                                                bf16_t* __restrict__ out) {
    __shared__ float part[4][DIN];
    int n = blockIdx.x;
    int w = threadIdx.x >> 6, lane = threadIdx.x & 63;
    int c0 = lane * 2;
    float a0 = 0.f, a1 = 0.f;
    int s0 = rowptr[n], s1 = rowptr[n + 1];
    int k = s0 + w;
    for (; k + 12 < s1; k += 16) {
        int2 e0 = csr[k], e1 = csr[k + 4], e2 = csr[k + 8], e3 = csr[k + 12];
        bf16x2 v0 = *(const bf16x2*)&H[(size_t)e0.x * DIN + c0];
        bf16x2 v1 = *(const bf16x2*)&H[(size_t)e1.x * DIN + c0];
        bf16x2 v2 = *(const bf16x2*)&H[(size_t)e2.x * DIN + c0];
        bf16x2 v3 = *(const bf16x2*)&H[(size_t)e3.x * DIN + c0];
        float c0f = __int_as_float(e0.y), c1f = __int_as_float(e1.y);
        float c2f = __int_as_float(e2.y), c3f = __int_as_float(e3.y);
        a0 += (float)v0[0] * c0f + (float)v1[0] * c1f + (float)v2[0] * c2f + (float)v3[0] * c3f;
        a1 += (float)v0[1] * c0f + (float)v1[1] * c1f + (float)v2[1] * c2f + (float)v3[1] * c3f;
    }
    for (; k < s1; k += 4) {
        int2 eA = csr[k];
        float cA = __int_as_float(eA.y);
        bf16x2 vA = *(const bf16x2*)&H[(size_t)eA.x * DIN + c0];
        a0 += (float)vA[0] * cA;
        a1 += (float)vA[1] * cA;
    }
    part[w][c0] = a0;
    part[w][c0 + 1] = a1;
    __syncthreads();
    if (threadIdx.x < 64) {
        int cc = threadIdx.x * 2;
        float b0 = part[0][cc] + part[1][cc] + part[2][cc] + part[3][cc];
        float b1 = part[0][cc + 1] + part[1][cc + 1] + part[2][cc + 1] + part[3][cc + 1];
        float di = dinv[n], sc = di * di;
        bf16x2 vs = *(const bf16x2*)&H[(size_t)n * DIN + cc];
        b0 += (float)vs[0] * sc;
        b1 += (float)vs[1] * sc;
        bf16x2 o;
        o[0] = (bf16_t)b0;
        o[1] = (bf16_t)b1;
        *(bf16x2*)&out[(size_t)n * DIN + cc] = o;
    }
}

// ---------------- 512-wide aggregate + bias + relu (+ LN), block per node, unroll-4 ----------------

template <bool DO_LN>
__global__ __launch_bounds__(256) void k_agg(const bf16_t* __restrict__ H,
                                             const int* __restrict__ rowptr,
                                             const int2* __restrict__ csr,
                                             const float* __restrict__ dinv,
                                             const float* __restrict__ bias,
                                             const float* __restrict__ gamma,
                                             const float* __restrict__ beta,
                                             bf16_t* __restrict__ out) {
    __shared__ float part[4][DH];
    __shared__ float rs[8];
    int n = blockIdx.x;
    int w = threadIdx.x >> 6, lane = threadIdx.x & 63;
    int c0 = lane * 8;
    float acc[8] = {0.f, 0.f, 0.f, 0.f, 0.f, 0.f, 0.f, 0.f};
    int s0 = rowptr[n], s1 = rowptr[n + 1];
    int k = s0 + w;
    for (; k + 12 < s1; k += 16) {
        int2 e0 = csr[k], e1 = csr[k + 4], e2 = csr[k + 8], e3 = csr[k + 12];
        bf16x8 v0 = *(const bf16x8*)&H[(size_t)e0.x * DH + c0];
        bf16x8 v1 = *(const bf16x8*)&H[(size_t)e1.x * DH + c0];
        bf16x8 v2 = *(const bf16x8*)&H[(size_t)e2.x * DH + c0];
        bf16x8 v3 = *(const bf16x8*)&H[(size_t)e3.x * DH + c0];
        float c0f = __int_as_float(e0.y), c1f = __int_as_float(e1.y);
        float c2f = __int_as_float(e2.y), c3f = __int_as_float(e3.y);
#pragma unroll
        for (int i = 0; i < 8; ++i)
            acc[i] += (float)v0[i] * c0f + (float)v1[i] * c1f +
                      (float)v2[i] * c2f + (float)v3[i] * c3f;
    }
    for (; k < s1; k += 4) {
        int2 eA = csr[k];
        float cA = __int_as_float(eA.y);
        bf16x8 vA = *(const bf16x8*)&H[(size_t)eA.x * DH + c0];
#pragma unroll
        for (int i = 0; i < 8; ++i) acc[i] += (float)vA[i] * cA;
    }
    *(f32x4*)&part[w][c0] = (f32x4){acc[0], acc[1], acc[2], acc[3]};
    *(f32x4*)&part[w][c0 + 4] = (f32x4){acc[4], acc[5], acc[6], acc[7]};
    __syncthreads();
    int cc = threadIdx.x * 2;
    f32x2 p0 = *(const f32x2*)&part[0][cc];
    f32x2 p1 = *(const f32x2*)&part[1][cc];
    f32x2 p2 = *(const f32x2*)&part[2][cc];
    f32x2 p3 = *(const f32x2*)&part[3][cc];
    float a0 = p0[0] + p1[0] + p2[0] + p3[0];
    float a1 = p0[1] + p1[1] + p2[1] + p3[1];
    float di = dinv[n], sc = di * di;
    bf16x2 vs = *(const bf16x2*)&H[(size_t)n * DH + cc];
    a0 += (float)vs[0] * sc;
    a1 += (float)vs[1] * sc;
    a0 = fmaxf(a0 + bias[cc], 0.f);
    a1 = fmaxf(a1 + bias[cc + 1], 0.f);
    bf16x2 o;
    if (DO_LN) {
        float s = a0 + a1, s2 = a0 * a0 + a1 * a1;
#pragma unroll
        for (int off = 32; off; off >>= 1) {
            s += __shfl_xor(s, off);
            s2 += __shfl_xor(s2, off);
        }
        if (lane == 0) {
            rs[w] = s;
            rs[4 + w] = s2;
        }
        __syncthreads();
        s = rs[0] + rs[1] + rs[2] + rs[3];
        s2 = rs[4] + rs[5] + rs[6] + rs[7];
        float mu = s * (1.f / 512.f);
        float var = s2 * (1.f / 512.f) - mu * mu;
        float r = rsqrtf(var + 1e-5f);
        o[0] = (bf16_t)((a0 - mu) * r * gamma[cc] + beta[cc]);
        o[1] = (bf16_t)((a1 - mu) * r * gamma[cc + 1] + beta[cc + 1]);
    } else {
        o[0] = (bf16_t)a0;
        o[1] = (bf16_t)a1;
    }
    *(bf16x2*)&out[(size_t)n * DH + cc] = o;
}

// ---------------- fused mean-pool + final linear ----------------

__global__ __launch_bounds__(256) void k_poolfin(const bf16_t* __restrict__ h,
                                                 const int* __restrict__ batch,
                                                 const float* __restrict__ linW,
                                                 const float* __restrict__ linb,
                                                 float* __restrict__ out) {
    __shared__ float pooled[DH];
    __shared__ float red[256];
    int g = blockIdx.x;
    int t = threadIdx.x;
    int lo = 0, hi = NN;
    while (lo < hi) {
        int mid = (lo + hi) >> 1;
        if (batch[mid] < g) lo = mid + 1;
        else hi = mid;
    }
    int start = lo;
    hi = NN;
    while (lo < hi) {
        int mid = (lo + hi) >> 1;
        if (batch[mid] < g + 1) lo = mid + 1;
        else hi = mid;
    }
    int end = lo;
    int c0 = t * 2;
    float a0 = 0.f, a1 = 0.f;
    for (int i = start; i < end; ++i) {
        bf16x2 v = *(const bf16x2*)&h[(size_t)i * DH + c0];
        a0 += (float)v[0];
        a1 += (float)v[1];
    }
    float inv = 1.f / fmaxf((float)(end - start), 1.0f);
    pooled[c0] = a0 * inv;
    pooled[c0 + 1] = a1 * inv;
    __syncthreads();
    int o = t & 15, c = t >> 4;
    float s = 0.f;
    int k0 = c * 32;
    for (int k = k0; k < k0 + 32; ++k) s += pooled[k] * linW[k * DOUT + o];
    red[t] = s;
    __syncthreads();
    if (t < DOUT) {
        float acc2 = 0.f;
        for (int cc = 0; cc < 16; ++cc) acc2 += red[cc * 16 + t];
        out[g * DOUT + t] = acc2 + linb[t];
    }
}

// ---------------- launch ----------------

extern "C" void kernel_launch(void* const* d_in, const int* in_sizes, int n_in,
                              void* d_out, int out_size, void* d_ws, size_t ws_size,
                              hipStream_t stream) {
    const float* x = (const float*)d_in[0];
    const int* ei = (const int*)d_in[1];
    const int* batch = (const int*)d_in[2];
    const float* W0 = (const float*)d_in[3];
    const float* b0 = (const float*)d_in[4];
    const float* g0 = (const float*)d_in[5];
    const float* be0 = (const float*)d_in[6];
    const float* Wh = (const float*)d_in[7];
    const float* bh = (const float*)d_in[8];
    const float* gh = (const float*)d_in[9];
    const float* beh = (const float*)d_in[10];
    const float* linW = (const float*)d_in[11];
    const float* linb = (const float*)d_in[12];
    float* out = (float*)d_out;

    // workspace layout
    bf16_t* lnbuf = (bf16_t*)d_ws;                        // NPAD*512 (ln out / final h)
    bf16_t* Cbf = lnbuf + (size_t)NPAD * DH;              // NPAD*512 (gemm out)
    bf16_t* lnx = Cbf + (size_t)NPAD * DH;                // NPAD*128 (layer-0 LN out)
    bf16_t* aggx = lnx + (size_t)NPAD * DIN;              // NPAD*128 (layer-0 agg out)
    bf16_t* Wt0 = aggx + (size_t)NPAD * DIN;              // 512*128
    bf16_t* Wth = Wt0 + 512 * DIN;                        // 3*512*512
    float* dinv = (float*)(Wth + 3 * DH * DH);            // N
    int* deg = (int*)(dinv + NN);                         // N
    int* rowptr = deg + NN;                               // N+1
    int* cursor = rowptr + NN + 1;                        // N (+pad for int2 align)
    int2* csr = (int2*)(cursor + NN + 1);                 // E

    const int* srcp = ei;
    const int* dstp = ei + NE;

    hipMemsetAsync(deg, 0, NN * sizeof(int), stream);
    k_prep<<<LNB + DEGB + WTB + CURB, 256, 0, stream>>>(x, g0, be0, lnx, dstp, deg,
                                                        W0, Wh, Wt0, Wth, cursor);
    k_scan<<<1, 1024, 0, stream>>>(deg, rowptr, dinv);
    k_fill_csr<<<(NE + 255) / 256, 256, 0, stream>>>(srcp, dstp, dinv, rowptr, cursor, csr);

    dim3 gemm_grid(NPAD / 64, DH / 64);

    // layer 0: agg(128-wide) -> GEMM(+bias+relu) -> LN for layer 1
    k_agg128<<<NN, 256, 0, stream>>>(lnx, rowptr, csr, dinv, aggx);
    k_gemm64<true><<<gemm_grid, 256, 0, stream>>>(aggx, Wt0, b0, Cbf, DIN);
    k_ln512<<<(NN + 3) / 4, 256, 0, stream>>>(Cbf, gh + 0 * DH, beh + 0 * DH, lnbuf);

    // layers 1..2: GEMM -> agg(+bias+relu+LN)
    for (int l = 0; l < 2; ++l) {
        k_gemm64<false><<<gemm_grid, 256, 0, stream>>>(lnbuf, Wth + (size_t)l * DH * DH,
                                                       nullptr, Cbf, DH);
        k_agg<true><<<NN, 256, 0, stream>>>(Cbf, rowptr, csr, dinv, bh + l * DH,
                                            gh + (l + 1) * DH, beh + (l + 1) * DH, lnbuf);
    }
    // layer 3: GEMM -> agg(+bias+relu), bf16 out
    k_gemm64<false><<<gemm_grid, 256, 0, stream>>>(lnbuf, Wth + (size_t)2 * DH * DH,
                                                   nullptr, Cbf, DH);
    k_agg<false><<<NN, 256, 0, stream>>>(Cbf, rowptr, csr, dinv, bh + 2 * DH,
                                         nullptr, nullptr, lnbuf);

    k_poolfin<<<NG, 256, 0, stream>>>(lnbuf, batch, linW, linb, out);
}

// Round 10
// 207.100 us; speedup vs baseline: 1.0356x; 1.0356x over previous
//
#include <hip/hip_runtime.h>

#define NN 10000
#define NE 160000
#define NG 512
#define DIN 128
#define DH 512
#define DOUT 16
#define NPAD 10112   // 158*64 (GEMM M-tile padding)

typedef __bf16 bf16_t;
typedef __attribute__((ext_vector_type(8))) __bf16 bf16x8;
typedef __attribute__((ext_vector_type(2))) __bf16 bf16x2;
typedef __attribute__((ext_vector_type(4))) float f32x4;
typedef __attribute__((ext_vector_type(2))) float f32x2;

// k_prep block ranges
#define LNB 2500                        // ln0: 4 rows/block
#define DEGB ((NE + 255) / 256)         // 625
#define WTE (512 * DIN + 3 * DH * DH)   // 851968
#define WTB ((WTE + 255) / 256)         // 3328
#define CURB ((NN + 255) / 256)         // 40

// ---------------- fused prep: ln0 + degree count + weight convert + cursor zero ----------------

__global__ __launch_bounds__(256) void k_prep(const float* __restrict__ x,
                                              const float* __restrict__ g0,
                                              const float* __restrict__ be0,
                                              bf16_t* __restrict__ lnx,
                                              const int* __restrict__ dst,
                                              int* __restrict__ deg,
                                              const float* __restrict__ W0,
                                              const float* __restrict__ Wh,
                                              bf16_t* __restrict__ Wt0,
                                              bf16_t* __restrict__ Wth,
                                              int* __restrict__ cursor) {
    int b = blockIdx.x;
    int tid = threadIdx.x;
    if (b < LNB) {
        int row = b * 4 + (tid >> 6);
        int lane = tid & 63;
        const float* xr = x + (size_t)row * DIN;
        float v0 = xr[lane], v1 = xr[lane + 64];
        float s = v0 + v1, s2 = v0 * v0 + v1 * v1;
#pragma unroll
        for (int off = 32; off; off >>= 1) {
            s += __shfl_xor(s, off);
            s2 += __shfl_xor(s2, off);
        }
        float mu = s * (1.f / 128.f);
        float var = s2 * (1.f / 128.f) - mu * mu;
        float r = rsqrtf(var + 1e-5f);
        bf16_t* yr = lnx + (size_t)row * DIN;
        yr[lane] = (bf16_t)((v0 - mu) * r * g0[lane] + be0[lane]);
        yr[lane + 64] = (bf16_t)((v1 - mu) * r * g0[lane + 64] + be0[lane + 64]);
    } else if (b < LNB + DEGB) {
        int e = (b - LNB) * 256 + tid;
        if (e < NE) atomicAdd(&deg[dst[e]], 1);
    } else if (b < LNB + DEGB + WTB) {
        int idx = (b - LNB - DEGB) * 256 + tid;
        if (idx < 512 * DIN) {
            int k = idx >> 9, n = idx & 511;   // W0 is [128][512]
            Wt0[n * DIN + k] = (bf16_t)W0[idx];
        } else if (idx < WTE) {
            int j = idx - 512 * DIN;
            int l = j >> 18;                   // / (512*512)
            int r2 = j & 262143;
            int k = r2 >> 9, n = r2 & 511;     // Wh[l] is [512][512]
            Wth[((size_t)l << 18) + n * DH + k] = (bf16_t)Wh[j];
        }
    } else {
        int i = (b - LNB - DEGB - WTB) * 256 + tid;
        if (i < NN) cursor[i] = 0;
    }
}

// ---------------- scan (rowptr) + dinv, wave-scan ----------------

__global__ __launch_bounds__(1024) void k_scan(const int* __restrict__ cnt,
                                               int* __restrict__ rowptr,
                                               float* __restrict__ dinv) {
    __shared__ int wsum[16];
    int tid = threadIdx.x, lane = tid & 63, wid = tid >> 6;
    const int PER = 10;
    int base = tid * PER;
    int local[PER];
    int s = 0;
#pragma unroll
    for (int i = 0; i < PER; ++i) {
        int idx = base + i;
        int v = (idx < NN) ? cnt[idx] : 0;
        if (idx < NN) dinv[idx] = rsqrtf((float)v + 1.0f);
        local[i] = s;
        s += v;
    }
    int mysum = s;
#pragma unroll
    for (int off = 1; off < 64; off <<= 1) {
        int v = __shfl_up(s, off);
        if (lane >= off) s += v;
    }
    if (lane == 63) wsum[wid] = s;
    __syncthreads();
    if (tid < 16) {
        int v = wsum[tid];
#pragma unroll
        for (int off = 1; off < 16; off <<= 1) {
            int u = __shfl_up(v, off);
            if (lane >= off) v += u;
        }
        wsum[tid] = v;
    }
    __syncthreads();
    int woff = (wid > 0) ? wsum[wid - 1] : 0;
    int excl = s - mysum + woff;
#pragma unroll
    for (int i = 0; i < PER; ++i) {
        int idx = base + i;
        if (idx < NN) rowptr[idx] = excl + local[i];
    }
    if (tid == 1023) rowptr[NN] = excl + mysum;
}

__global__ void k_fill_csr(const int* __restrict__ src, const int* __restrict__ dst,
                           const float* __restrict__ dinv, const int* __restrict__ rowptr,
                           int* __restrict__ cursor, int2* __restrict__ csr) {
    int e = blockIdx.x * blockDim.x + threadIdx.x;
    if (e >= NE) return;
    int s = src[e], d = dst[e];
    int pos = atomicAdd(&cursor[d], 1);
    csr[rowptr[d] + pos] = make_int2(s, __float_as_int(dinv[s] * dinv[d]));
}

// ---------------- standalone layernorm 512-wide bf16 -> bf16 ----------------

__global__ __launch_bounds__(256) void k_ln512(const bf16_t* __restrict__ x,
                                               const float* __restrict__ g,
                                               const float* __restrict__ b,
                                               bf16_t* __restrict__ y) {
    int row = blockIdx.x * 4 + (threadIdx.x >> 6);
    int lane = threadIdx.x & 63;
    if (row >= NN) return;
    int c0 = lane * 8;
    bf16x8 v = *(const bf16x8*)&x[(size_t)row * DH + c0];
    float f[8];
    float s = 0.f, s2 = 0.f;
#pragma unroll
    for (int i = 0; i < 8; ++i) {
        f[i] = (float)v[i];
        s += f[i];
        s2 += f[i] * f[i];
    }
#pragma unroll
    for (int off = 32; off; off >>= 1) {
        s += __shfl_xor(s, off);
        s2 += __shfl_xor(s2, off);
    }
    float mu = s * (1.f / 512.f);
    float var = s2 * (1.f / 512.f) - mu * mu;
    float r = rsqrtf(var + 1e-5f);
    f32x4 g0 = *(const f32x4*)&g[c0], g1 = *(const f32x4*)&g[c0 + 4];
    f32x4 b0 = *(const f32x4*)&b[c0], b1 = *(const f32x4*)&b[c0 + 4];
    bf16x8 o;
#pragma unroll
    for (int i = 0; i < 4; ++i) {
        o[i] = (bf16_t)((f[i] - mu) * r * g0[i] + b0[i]);
        o[i + 4] = (bf16_t)((f[i + 4] - mu) * r * g1[i] + b1[i]);
    }
    *(bf16x8*)&y[(size_t)row * DH + c0] = o;
}

// ---------------- bf16 MFMA GEMM: BM=64 BN=64 BK=64, 4 waves each 32x32 ----------------
// (round-4 exact: single-buffered, LDS XOR chunk swizzle, pre-swizzled global source)

template <bool EPI>
__global__ __launch_bounds__(256) void k_gemm64(const bf16_t* __restrict__ A,
                                                const bf16_t* __restrict__ Bt,
                                                const float* __restrict__ bias,
                                                bf16_t* __restrict__ C, int K) {
    __shared__ bf16_t As[64 * 64];
    __shared__ bf16_t Bs[64 * 64];
    int tid = threadIdx.x;
    int lane = tid & 63, w = tid >> 6;
    int row0 = blockIdx.x * 64, col0 = blockIdx.y * 64;
    int wm = w >> 1, wn = w & 1;

    f32x4 acc[2][2];
#pragma unroll
    for (int i = 0; i < 2; ++i)
#pragma unroll
        for (int j = 0; j < 2; ++j) acc[i][j] = (f32x4){0.f, 0.f, 0.f, 0.f};

    int lr = lane >> 3;
    int lc = lane & 7;

    for (int kt = 0; kt < K; kt += 64) {
#pragma unroll
        for (int i = 0; i < 2; ++i) {
            int r = w * 16 + i * 8 + lr;
            int cg = lc ^ (r & 7);
            const bf16_t* srca = A + (size_t)(row0 + r) * K + kt + cg * 8;
            __builtin_amdgcn_global_load_lds(
                (const __attribute__((address_space(1))) void*)srca,
                (__attribute__((address_space(3))) void*)(As + (w * 16 + i * 8) * 64),
                16, 0, 0);
            const bf16_t* srcb = Bt + (size_t)(col0 + r) * K + kt + cg * 8;
            __builtin_amdgcn_global_load_lds(
                (const __attribute__((address_space(1))) void*)srcb,
                (__attribute__((address_space(3))) void*)(Bs + (w * 16 + i * 8) * 64),
                16, 0, 0);
        }
        __syncthreads();
#pragma unroll
        for (int ks = 0; ks < 2; ++ks) {
            bf16x8 af[2], bfr[2];
#pragma unroll
            for (int mi = 0; mi < 2; ++mi) {
                int mr = wm * 32 + mi * 16 + (lane & 15);
                int c = (ks * 4 + (lane >> 4)) ^ (mr & 7);
                af[mi] = *(const bf16x8*)&As[mr * 64 + c * 8];
            }
#pragma unroll
            for (int ni = 0; ni < 2; ++ni) {
                int nr = wn * 32 + ni * 16 + (lane & 15);
                int c = (ks * 4 + (lane >> 4)) ^ (nr & 7);
                bfr[ni] = *(const bf16x8*)&Bs[nr * 64 + c * 8];
            }
#pragma unroll
            for (int mi = 0; mi < 2; ++mi)
#pragma unroll
                for (int ni = 0; ni < 2; ++ni)
                    acc[mi][ni] = __builtin_amdgcn_mfma_f32_16x16x32_bf16(
                        af[mi], bfr[ni], acc[mi][ni], 0, 0, 0);
        }
        __syncthreads();
    }
#pragma unroll
    for (int mi = 0; mi < 2; ++mi)
#pragma unroll
        for (int ni = 0; ni < 2; ++ni) {
            int col = col0 + wn * 32 + ni * 16 + (lane & 15);
            float bv = EPI ? bias[col] : 0.f;
#pragma unroll
            for (int q = 0; q < 4; ++q) {
                int row = row0 + wm * 32 + mi * 16 + (lane >> 4) * 4 + q;
                float v = acc[mi][ni][q];
                if (EPI) v = fmaxf(v + bv, 0.f);
                C[(size_t)row * DH + col] = (bf16_t)v;
            }
        }
}

// ---------------- layer-0 aggregate, 128-wide, block per node, unroll-4 ----------------

__global__ __launch_bounds__(256) void k_agg128(const bf16_t* __restrict__ H,
                                                const int* __restrict__ rowptr,
                                                const int2* __restrict__ csr,
                                                const float* __restrict__ dinv,
                                                bf16_t* __restrict__ out) {
    __shared__ float part[4][DIN];
    int n = blockIdx.x;
    int w = threadIdx.x >> 6, lane = threadIdx.x & 63;
    int c0 = lane * 2;
    float a0 = 0.f, a1 = 0.f;
    int s0 = rowptr[n], s1 = rowptr[n + 1];
    int k = s0 + w;
    for (; k + 12 < s1; k += 16) {
        int2 e0 = csr[k], e1 = csr[k + 4], e2 = csr[k + 8], e3 = csr[k + 12];
        bf16x2 v0 = *(const bf16x2*)&H[(size_t)e0.x * DIN + c0];
        bf16x2 v1 = *(const bf16x2*)&H[(size_t)e1.x * DIN + c0];
        bf16x2 v2 = *(const bf16x2*)&H[(size_t)e2.x * DIN + c0];
        bf16x2 v3 = *(const bf16x2*)&H[(size_t)e3.x * DIN + c0];
        float c0f = __int_as_float(e0.y), c1f = __int_as_float(e1.y);
        float c2f = __int_as_float(e2.y), c3f = __int_as_float(e3.y);
        a0 += (float)v0[0] * c0f + (float)v1[0] * c1f + (float)v2[0] * c2f + (float)v3[0] * c3f;
        a1 += (float)v0[1] * c0f + (float)v1[1] * c1f + (float)v2[1] * c2f + (float)v3[1] * c3f;
    }
    for (; k < s1; k += 4) {
        int2 eA = csr[k];
        float cA = __int_as_float(eA.y);
        bf16x2 vA = *(const bf16x2*)&H[(size_t)eA.x * DIN + c0];
        a0 += (float)vA[0] * cA;
        a1 += (float)vA[1] * cA;
    }
    part[w][c0] = a0;
    part[w][c0 + 1] = a1;
    __syncthreads();
    if (threadIdx.x < 64) {
        int cc = threadIdx.x * 2;
        float b0 = part[0][cc] + part[1][cc] + part[2][cc] + part[3][cc];
        float b1 = part[0][cc + 1] + part[1][cc + 1] + part[2][cc + 1] + part[3][cc + 1];
        float di = dinv[n], sc = di * di;
        bf16x2 vs = *(const bf16x2*)&H[(size_t)n * DIN + cc];
        b0 += (float)vs[0] * sc;
        b1 += (float)vs[1] * sc;
        bf16x2 o;
        o[0] = (bf16_t)b0;
        o[1] = (bf16_t)b1;
        *(bf16x2*)&out[(size_t)n * DIN + cc] = o;
    }
}

// ---------------- 512-wide aggregate + bias + relu (+ LN), block per node, unroll-4 ----------------

template <bool DO_LN>
__global__ __launch_bounds__(256) void k_agg(const bf16_t* __restrict__ H,
                                             const int* __restrict__ rowptr,
                                             const int2* __restrict__ csr,
                                             const float* __restrict__ dinv,
                                             const float* __restrict__ bias,
                                             const float* __restrict__ gamma,
                                             const float* __restrict__ beta,
                                             bf16_t* __restrict__ out) {
    __shared__ float part[4][DH];
    __shared__ float rs[8];
    int n = blockIdx.x;
    int w = threadIdx.x >> 6, lane = threadIdx.x & 63;
    int c0 = lane * 8;
    float acc[8] = {0.f, 0.f, 0.f, 0.f, 0.f, 0.f, 0.f, 0.f};
    int s0 = rowptr[n], s1 = rowptr[n + 1];
    int k = s0 + w;
    for (; k + 12 < s1; k += 16) {
        int2 e0 = csr[k], e1 = csr[k + 4], e2 = csr[k + 8], e3 = csr[k + 12];
        bf16x8 v0 = *(const bf16x8*)&H[(size_t)e0.x * DH + c0];
        bf16x8 v1 = *(const bf16x8*)&H[(size_t)e1.x * DH + c0];
        bf16x8 v2 = *(const bf16x8*)&H[(size_t)e2.x * DH + c0];
        bf16x8 v3 = *(const bf16x8*)&H[(size_t)e3.x * DH + c0];
        float c0f = __int_as_float(e0.y), c1f = __int_as_float(e1.y);
        float c2f = __int_as_float(e2.y), c3f = __int_as_float(e3.y);
#pragma unroll
        for (int i = 0; i < 8; ++i)
            acc[i] += (float)v0[i] * c0f + (float)v1[i] * c1f +
                      (float)v2[i] * c2f + (float)v3[i] * c3f;
    }
    for (; k < s1; k += 4) {
        int2 eA = csr[k];
        float cA = __int_as_float(eA.y);
        bf16x8 vA = *(const bf16x8*)&H[(size_t)eA.x * DH + c0];
#pragma unroll
        for (int i = 0; i < 8; ++i) acc[i] += (float)vA[i] * cA;
    }
    *(f32x4*)&part[w][c0] = (f32x4){acc[0], acc[1], acc[2], acc[3]};
    *(f32x4*)&part[w][c0 + 4] = (f32x4){acc[4], acc[5], acc[6], acc[7]};
    __syncthreads();
    int cc = threadIdx.x * 2;
    f32x2 p0 = *(const f32x2*)&part[0][cc];
    f32x2 p1 = *(const f32x2*)&part[1][cc];
    f32x2 p2 = *(const f32x2*)&part[2][cc];
    f32x2 p3 = *(const f32x2*)&part[3][cc];
    float a0 = p0[0] + p1[0] + p2[0] + p3[0];
    float a1 = p0[1] + p1[1] + p2[1] + p3[1];
    float di = dinv[n], sc = di * di;
    bf16x2 vs = *(const bf16x2*)&H[(size_t)n * DH + cc];
    a0 += (float)vs[0] * sc;
    a1 += (float)vs[1] * sc;
    a0 = fmaxf(a0 + bias[cc], 0.f);
    a1 = fmaxf(a1 + bias[cc + 1], 0.f);
    bf16x2 o;
    if (DO_LN) {
        float s = a0 + a1, s2 = a0 * a0 + a1 * a1;
#pragma unroll
        for (int off = 32; off; off >>= 1) {
            s += __shfl_xor(s, off);
            s2 += __shfl_xor(s2, off);
        }
        if (lane == 0) {
            rs[w] = s;
            rs[4 + w] = s2;
        }
        __syncthreads();
        s = rs[0] + rs[1] + rs[2] + rs[3];
        s2 = rs[4] + rs[5] + rs[6] + rs[7];
        float mu = s * (1.f / 512.f);
        float var = s2 * (1.f / 512.f) - mu * mu;
        float r = rsqrtf(var + 1e-5f);
        o[0] = (bf16_t)((a0 - mu) * r * gamma[cc] + beta[cc]);
        o[1] = (bf16_t)((a1 - mu) * r * gamma[cc + 1] + beta[cc + 1]);
    } else {
        o[0] = (bf16_t)a0;
        o[1] = (bf16_t)a1;
    }
    *(bf16x2*)&out[(size_t)n * DH + cc] = o;
}

// ---------------- fused mean-pool + final linear ----------------

__global__ __launch_bounds__(256) void k_poolfin(const bf16_t* __restrict__ h,
                                                 const int* __restrict__ batch,
                                                 const float* __restrict__ linW,
                                                 const float* __restrict__ linb,
                                                 float* __restrict__ out) {
    __shared__ float pooled[DH];
    __shared__ float red[256];
    int g = blockIdx.x;
    int t = threadIdx.x;
    int lo = 0, hi = NN;
    while (lo < hi) {
        int mid = (lo + hi) >> 1;
        if (batch[mid] < g) lo = mid + 1;
        else hi = mid;
    }
    int start = lo;
    hi = NN;
    while (lo < hi) {
        int mid = (lo + hi) >> 1;
        if (batch[mid] < g + 1) lo = mid + 1;
        else hi = mid;
    }
    int end = lo;
    int c0 = t * 2;
    float a0 = 0.f, a1 = 0.f;
    for (int i = start; i < end; ++i) {
        bf16x2 v = *(const bf16x2*)&h[(size_t)i * DH + c0];
        a0 += (float)v[0];
        a1 += (float)v[1];
    }
    float inv = 1.f / fmaxf((float)(end - start), 1.0f);
    pooled[c0] = a0 * inv;
    pooled[c0 + 1] = a1 * inv;
    __syncthreads();
    int o = t & 15, c = t >> 4;
    float s = 0.f;
    int k0 = c * 32;
    for (int k = k0; k < k0 + 32; ++k) s += pooled[k] * linW[k * DOUT + o];
    red[t] = s;
    __syncthreads();
    if (t < DOUT) {
        float acc2 = 0.f;
        for (int cc = 0; cc < 16; ++cc) acc2 += red[cc * 16 + t];
        out[g * DOUT + t] = acc2 + linb[t];
    }
}

// ---------------- launch ----------------

extern "C" void kernel_launch(void* const* d_in, const int* in_sizes, int n_in,
                              void* d_out, int out_size, void* d_ws, size_t ws_size,
                              hipStream_t stream) {
    const float* x = (const float*)d_in[0];
    const int* ei = (const int*)d_in[1];
    const int* batch = (const int*)d_in[2];
    const float* W0 = (const float*)d_in[3];
    const float* b0 = (const float*)d_in[4];
    const float* g0 = (const float*)d_in[5];
    const float* be0 = (const float*)d_in[6];
    const float* Wh = (const float*)d_in[7];
    const float* bh = (const float*)d_in[8];
    const float* gh = (const float*)d_in[9];
    const float* beh = (const float*)d_in[10];
    const float* linW = (const float*)d_in[11];
    const float* linb = (const float*)d_in[12];
    float* out = (float*)d_out;

    // workspace layout
    bf16_t* lnbuf = (bf16_t*)d_ws;                        // NPAD*512 (ln out / final h)
    bf16_t* Cbf = lnbuf + (size_t)NPAD * DH;              // NPAD*512 (gemm out)
    bf16_t* lnx = Cbf + (size_t)NPAD * DH;                // NPAD*128 (layer-0 LN out)
    bf16_t* aggx = lnx + (size_t)NPAD * DIN;              // NPAD*128 (layer-0 agg out)
    bf16_t* Wt0 = aggx + (size_t)NPAD * DIN;              // 512*128
    bf16_t* Wth = Wt0 + 512 * DIN;                        // 3*512*512
    float* dinv = (float*)(Wth + 3 * DH * DH);            // N
    int* deg = (int*)(dinv + NN);                         // N
    int* rowptr = deg + NN;                               // N+1
    int* cursor = rowptr + NN + 1;                        // N (+pad for int2 align)
    int2* csr = (int2*)(cursor + NN + 1);                 // E

    const int* srcp = ei;
    const int* dstp = ei + NE;

    hipMemsetAsync(deg, 0, NN * sizeof(int), stream);
    k_prep<<<LNB + DEGB + WTB + CURB, 256, 0, stream>>>(x, g0, be0, lnx, dstp, deg,
                                                        W0, Wh, Wt0, Wth, cursor);
    k_scan<<<1, 1024, 0, stream>>>(deg, rowptr, dinv);
    k_fill_csr<<<(NE + 255) / 256, 256, 0, stream>>>(srcp, dstp, dinv, rowptr, cursor, csr);

    dim3 gemm_grid(NPAD / 64, DH / 64);

    // layer 0: agg(128-wide) -> GEMM(+bias+relu) -> LN for layer 1
    k_agg128<<<NN, 256, 0, stream>>>(lnx, rowptr, csr, dinv, aggx);
    k_gemm64<true><<<gemm_grid, 256, 0, stream>>>(aggx, Wt0, b0, Cbf, DIN);
    k_ln512<<<(NN + 3) / 4, 256, 0, stream>>>(Cbf, gh + 0 * DH, beh + 0 * DH, lnbuf);

    // layers 1..2: GEMM -> agg(+bias+relu+LN)
    for (int l = 0; l < 2; ++l) {
        k_gemm64<false><<<gemm_grid, 256, 0, stream>>>(lnbuf, Wth + (size_t)l * DH * DH,
                                                       nullptr, Cbf, DH);
        k_agg<true><<<NN, 256, 0, stream>>>(Cbf, rowptr, csr, dinv, bh + l * DH,
                                            gh + (l + 1) * DH, beh + (l + 1) * DH, lnbuf);
    }
    // layer 3: GEMM -> agg(+bias+relu), bf16 out
    k_gemm64<false><<<gemm_grid, 256, 0, stream>>>(lnbuf, Wth + (size_t)2 * DH * DH,
                                                   nullptr, Cbf, DH);
    k_agg<false><<<NN, 256, 0, stream>>>(Cbf, rowptr, csr, dinv, bh + 2 * DH,
                                         nullptr, nullptr, lnbuf);

    k_poolfin<<<NG, 256, 0, stream>>>(lnbuf, batch, linW, linb, out);
}